// Round 18
// baseline (279.628 us; speedup 1.0000x reference)
//
#include <hip/hip_runtime.h>
#include <hip/hip_bf16.h>

#define N_NODES 16000
#define IN_F 128
#define HID 64
#define BATCH 32
#define NPAIR 128
#define DRES 100
#define NCLS 10

// workspace layout (float offsets)
#define NF_OFF     0
#define WA1_OFF    16000                 // conv1 A-frag bf16 pairs (512 uint)
#define WT2B_OFF   16800                 // [200 kp][32 oc] packed bf16 pairs (6400 uint)
#define CNT_OFF    23200                 // [4] grid-barrier counters (zeroed by k_bz)
#define MAXB_OFF   23264                 // [64] per-img max bits (zeroed by k_bz)
#define IMGSP_OFF  23328                 // [32][2][104][104] padded
#define POOL1P_OFF 715552                // [32][16][54][56] padded
#define POOL2_OFF  2263840               // [32][32][25][25]

#define NFILT_BLK  125                   // filt blocks (4 waves x 32 nodes each)
#define GRID_N     256                   // one block per CU -> co-residency guaranteed

typedef short short8 __attribute__((ext_vector_type(8)));
typedef float f32x16 __attribute__((ext_vector_type(16)));

static __device__ __forceinline__ unsigned short f2b(float f) {
    __hip_bfloat16 h = __float2bfloat16(f);
    return *reinterpret_cast<unsigned short*>(&h);
}
static __device__ __forceinline__ unsigned int pk2(float a, float b) {
    return (unsigned int)f2b(a) | ((unsigned int)f2b(b) << 16);
}

// conv2: element offset of k=(ic,kh,kw) within inb[16][6][56]
#define COFF(k) (((k)/25)*336 + (((k)%25)/5)*56 + ((k)%25)%5)
// conv1: element offset of k within inbz[2][6][104]; k>=50 -> zero zone @1248
#define C1OFF(k) ((k) < 50 ? ((k)/25)*624 + ((((k)%25)/5))*104 + (((k)%25)%5) : 1248)

// ---------------- software grid barrier (graph-capture safe) ----------------
// All 256 blocks are co-resident (1 block/CU at any VGPR<=512, LDS 21.5KB).
// release fence (L2 writeback) -> device-scope arrive -> spin -> acquire fence
// (L2 invalidate): provides the cross-XCD coherence a kernel boundary would.
static __device__ __forceinline__ void gridbar(unsigned int* cnt, int t) {
    __syncthreads();
    if (t == 0) {
        __threadfence();
        __hip_atomic_fetch_add(cnt, 1u, __ATOMIC_RELEASE, __HIP_MEMORY_SCOPE_AGENT);
        while (__hip_atomic_load(cnt, __ATOMIC_ACQUIRE, __HIP_MEMORY_SCOPE_AGENT) < GRID_N)
            __builtin_amdgcn_s_sleep(2);
    }
    __syncthreads();
    __threadfence();
}

// ---------------- pre-kernel: zero barrier counters + maxb ----------------
__global__ __launch_bounds__(256) void k_bz(unsigned int* __restrict__ cnt,
                                            unsigned int* __restrict__ maxb)
{
    int t = threadIdx.x;
    if (t < 4) cnt[t] = 0u;
    else if (t < 68) maxb[t - 4] = 0u;
}

union SMem {
    struct { float sb[NPAIR]; float sp[NPAIR]; float wm[4]; } B;
    unsigned short c1[2][1472];
    unsigned short c2[2][5376];
    float fcpart[4];
};

// ---------------- mega-kernel: all 5 phases, 4 software grid barriers ----------------
__global__ __launch_bounds__(256) void k_mega(
    const float* __restrict__ x, const int* __restrict__ pi0,
    const int* __restrict__ pi1, const float* __restrict__ w1,
    const float* __restrict__ b1, const float* __restrict__ w2,
    const float* __restrict__ b2, const float* __restrict__ c1w,
    const float* __restrict__ c1b, const float* __restrict__ c2w,
    const float* __restrict__ c2b, const float* __restrict__ oww,
    const float* __restrict__ owb, float* __restrict__ out, float* __restrict__ ws)
{
    __shared__ SMem sm;

    float*        nf     = ws + NF_OFF;
    unsigned int* wA1    = (unsigned int*)(ws + WA1_OFF);
    unsigned int* wT2b   = (unsigned int*)(ws + WT2B_OFF);
    unsigned int* cnt    = (unsigned int*)(ws + CNT_OFF);
    unsigned int* maxb   = (unsigned int*)(ws + MAXB_OFF);
    float*        imgs_p = ws + IMGSP_OFF;
    float*        pool1p = ws + POOL1P_OFF;
    float*        pool2  = ws + POOL2_OFF;
    float*        out_nf = out + BATCH * NCLS;

    int bid = blockIdx.x, t = threadIdx.x;

    // ============ Phase A: filt MLP (MFMA) | weight prep | border zero ============
    if (bid < NFILT_BLK) {
        int wave = t >> 6, lane = t & 63;
        int n0 = ((bid << 2) + wave) * 32;
        int hh = lane >> 5, smn = lane & 31;
        const float* xr = x + (size_t)(n0 + smn) * IN_F + hh * 8;
        const float* wbase = w1 + hh * 512 + smn;

        f32x16 acc0 = {0.f,0.f,0.f,0.f,0.f,0.f,0.f,0.f,0.f,0.f,0.f,0.f,0.f,0.f,0.f,0.f};
        f32x16 acc1 = {0.f,0.f,0.f,0.f,0.f,0.f,0.f,0.f,0.f,0.f,0.f,0.f,0.f,0.f,0.f,0.f};
        #pragma unroll
        for (int s = 0; s < 8; ++s) {
            float4 v0 = *(const float4*)(xr + s * 16);
            float4 v1 = *(const float4*)(xr + s * 16 + 4);
            union { short8 v; unsigned int u[4]; } a;
            a.u[0] = pk2(v0.x, v0.y);
            a.u[1] = pk2(v0.z, v0.w);
            a.u[2] = pk2(v1.x, v1.y);
            a.u[3] = pk2(v1.z, v1.w);
            union { short8 v; unsigned int u[4]; } b0f, b1f;
            #pragma unroll
            for (int r = 0; r < 4; ++r) {
                float wa0 = wbase[s * 1024 + r * 128];
                float wb0 = wbase[s * 1024 + r * 128 + 64];
                float wa1 = wbase[s * 1024 + r * 128 + 32];
                float wb1v = wbase[s * 1024 + r * 128 + 96];
                b0f.u[r] = pk2(wa0, wb0);
                b1f.u[r] = pk2(wa1, wb1v);
            }
            acc0 = __builtin_amdgcn_mfma_f32_32x32x16_bf16(a.v, b0f.v, acc0, 0, 0, 0);
            acc1 = __builtin_amdgcn_mfma_f32_32x32x16_bf16(a.v, b1f.v, acc1, 0, 0, 0);
        }
        int h0 = smn, h1 = 32 + smn;
        float b10 = b1[h0], b11 = b1[h1], w20 = w2[h0], w21 = w2[h1];
        float q[16];
        #pragma unroll
        for (int r = 0; r < 16; ++r)
            q[r] = fmaxf(acc0[r] + b10, 0.f) * w20 + fmaxf(acc1[r] + b11, 0.f) * w21;
        #pragma unroll
        for (int off = 1; off < 32; off <<= 1) {
            #pragma unroll
            for (int r = 0; r < 16; ++r)
                q[r] += __shfl_xor(q[r], off, 64);
        }
        if (smn == 0) {
            float b2v = b2[0];
            #pragma unroll
            for (int r = 0; r < 16; ++r) {
                int m = (r & 3) + 8 * (r >> 2) + 4 * hh;
                float f = 1.f / (1.f + expf(-(q[r] + b2v)));
                nf[n0 + m] = f;
                out_nf[n0 + m] = f;
            }
        }
    } else if (bid == NFILT_BLK) {
        for (int i = t; i < 512; i += 256) {
            int r = i & 3, m = (i >> 2) & 15, kg = (i >> 6) & 1, s = i >> 7;
            int k0 = s * 16 + kg * 8 + 2 * r;
            float f0 = (k0 < 50) ? c1w[m * 50 + k0] : 0.f;
            float f1 = (k0 + 1 < 50) ? c1w[m * 50 + k0 + 1] : 0.f;
            wA1[i] = pk2(f0, f1);
        }
    } else if (bid == NFILT_BLK + 1) {
        for (int i = t; i < 6400; i += 256) {
            int kp = i >> 5, oc = i & 31;
            int k0 = 2 * kp, k1 = k0 + 1;
            float f0 = c2w[(oc * 16 + k0 / 25) * 25 + k0 % 25];
            float f1 = c2w[(oc * 16 + k1 / 25) * 25 + k1 % 25];
            wT2b[i] = pk2(f0, f1);
        }
    } else {
        // border-only zeroing over 129 blocks: imgs borders [0,52224), pool1p [52224,320512)
        for (int idx = (bid - (NFILT_BLK + 2)) * 256 + t; idx < 320512; idx += 33024) {
            if (idx < 52224) {
                int img = idx / 816, i = idx % 816;
                int row, col;
                if (i < 416) { int r4 = i / 104; row = (r4 < 2) ? r4 : 100 + r4; col = i % 104; }
                else { int j = i - 416; row = 2 + j / 4; int c4 = j % 4; col = (c4 < 2) ? c4 : 100 + c4; }
                imgs_p[(size_t)img * 10816 + row * 104 + col] = 0.f;
            } else {
                int u2 = idx - 52224;
                int ch = u2 / 524, i = u2 % 524;
                int row, col;
                if (i < 224) { int r4 = i / 56; row = (r4 < 2) ? r4 : 50 + r4; col = i % 56; }
                else { int j = i - 224; row = 2 + j / 6; int c6 = j % 6; col = (c6 < 2) ? c6 : 50 + c6; }
                pool1p[(size_t)ch * 3024 + row * 56 + col] = 0.f;
            }
        }
    }

    gridbar(&cnt[0], t);

    // ============ Phase B: persistence image (512 units, 2 per block) ============
    for (int u = bid; u < 512; u += GRID_N) {
        __syncthreads();
        int img = (u & 7) * 8 + ((u >> 3) & 7);
        int q = (u >> 6) & 3;
        int rh = u >> 8;
        int b = img >> 1, c = img & 1;
        const int* pi = c ? pi1 : pi0;
        if (t < NPAIR) {
            int i0 = pi[(b * NPAIR + t) * 2 + 0];
            int i1 = pi[(b * NPAIR + t) * 2 + 1];
            float f0 = nf[i0], f1 = nf[i1];
            sm.B.sb[t] = f0;
            sm.B.sp[t] = f1 - f0;
        }
        __syncthreads();
        bool act = t < 169;
        int ti = t / 13, tj = t % 13;
        float acc[4][2] = {};
        if (act) {
            float ci[4];
            #pragma unroll
            for (int r = 0; r < 4; ++r) ci[r] = (float)(ti + 13 * (rh * 4 + r)) * 0.01f;
            float cj0 = (float)(q * 25 + tj) * 0.01f;
            float cj1 = (float)(q * 25 + tj + 13) * 0.01f;
            for (int p = 0; p < NPAIR; ++p) {
                float bb = sm.B.sb[p], pp = sm.B.sp[p];
                float d0 = pp - cj0, d1 = pp - cj1;
                float e0 = __expf(-d0 * d0), e1 = __expf(-d1 * d1);
                #pragma unroll
                for (int r = 0; r < 4; ++r) {
                    float d = bb - ci[r];
                    float eb = __expf(-d * d);
                    acc[r][0] = fmaf(eb, e0, acc[r][0]);
                    acc[r][1] = fmaf(eb, e1, acc[r][1]);
                }
            }
        }
        float lmax = 0.f;
        if (act) {
            float* dst = imgs_p + (size_t)img * 10816 + 2 * 104 + 2 + q * 25;
            #pragma unroll
            for (int r = 0; r < 4; ++r) {
                int i = ti + 13 * (rh * 4 + r);
                if (i < DRES) {
                    dst[i * 104 + tj] = acc[r][0];
                    lmax = fmaxf(lmax, acc[r][0]);
                    if (tj < 12) {
                        dst[i * 104 + tj + 13] = acc[r][1];
                        lmax = fmaxf(lmax, acc[r][1]);
                    }
                }
            }
        }
        #pragma unroll
        for (int off = 32; off > 0; off >>= 1)
            lmax = fmaxf(lmax, __shfl_xor(lmax, off, 64));
        if ((t & 63) == 0) sm.B.wm[t >> 6] = lmax;
        __syncthreads();
        if (t == 0) {
            float bm = fmaxf(fmaxf(sm.B.wm[0], sm.B.wm[1]),
                             fmaxf(sm.B.wm[2], sm.B.wm[3]));
            atomicMax(&maxb[img], __float_as_uint(bm));
        }
    }

    gridbar(&cnt[1], t);

    // ============ Phase C: conv1 via MFMA (1600 half-units, 2 per block-iter) ============
    for (int u = bid; u < 800; u += GRID_N) {
        __syncthreads();
        int half = t >> 7, lt = t & 127;
        int g = 2 * u + half;
        int b = (g & 7) * 4 + ((g >> 3) & 3);
        int py = g >> 5;
        {
            float sc0 = 1.f / __uint_as_float(maxb[b * 2 + 0]);
            float sc1 = 1.f / __uint_as_float(maxb[b * 2 + 1]);
            const float* s0 = imgs_p + (size_t)(b * 2 + 0) * 10816 + (2 * py) * 104;
            const float* s1 = s0 + 10816;
            unsigned int* z32 = (unsigned int*)sm.c1[half];
            for (int i = lt; i < 736; i += 128) {
                unsigned int val = 0u;
                if (i < 312) {
                    int s2 = 2 * i; int r = s2 / 104, cc = s2 % 104;
                    float2 v = *(const float2*)(s0 + r * 104 + cc);
                    val = pk2(v.x * sc0, v.y * sc0);
                } else if (i < 624) {
                    int s2 = 2 * i - 624; int r = s2 / 104, cc = s2 % 104;
                    float2 v = *(const float2*)(s1 + r * 104 + cc);
                    val = pk2(v.x * sc1, v.y * sc1);
                }
                z32[i] = val;
            }
        }
        __syncthreads();
        int lane = lt & 63;
        int h = lt >> 6;
        int hh = lane >> 5;
        int smn = lane & 31;
        int q = lane & 3;
        int cl = smn >> 2;
        int laneoff = (q >> 1) * 104 + 2 * cl + (q & 1);

        uint4 z4 = {0u, 0u, 0u, 0u};
        union { short8 v; uint4 qd; } afr[4];
        #pragma unroll
        for (int s = 0; s < 4; ++s)
            afr[s].qd = (smn < 16) ? *(const uint4*)(wA1 + ((s * 2 + hh) * 16 + smn) * 4) : z4;

        float bb[8];
        #pragma unroll
        for (int r = 0; r < 8; ++r)
            bb[r] = c1b[(r & 3) + 8 * (r >> 2) + 4 * hh];

        #pragma unroll
        for (int tt = 0; tt < 4; ++tt) {
            int t_ = h + 2 * tt;
            if (t_ < 7) {
                const unsigned short* bp = sm.c1[half] + laneoff + 16 * t_;
                f32x16 acc = {0.f,0.f,0.f,0.f,0.f,0.f,0.f,0.f,0.f,0.f,0.f,0.f,0.f,0.f,0.f,0.f};
                #pragma unroll
                for (int s = 0; s < 4; ++s) {
                    unsigned short ub[8];
                    #pragma unroll
                    for (int e = 0; e < 8; ++e) {
                        int off = hh ? C1OFF(16 * s + 8 + e) : C1OFF(16 * s + e);
                        ub[e] = bp[off];
                    }
                    union { short8 v; unsigned int u[4]; } bf;
                    #pragma unroll
                    for (int r = 0; r < 4; ++r)
                        bf.u[r] = (unsigned int)ub[2 * r] | ((unsigned int)ub[2 * r + 1] << 16);
                    acc = __builtin_amdgcn_mfma_f32_32x32x16_bf16(afr[s].v, bf.v, acc, 0, 0, 0);
                }
                int pc = 8 * t_ + cl;
                #pragma unroll
                for (int r = 0; r < 8; ++r) {
                    float vr = acc[r];
                    vr = fmaxf(vr, __shfl_xor(vr, 1, 64));
                    vr = fmaxf(vr, __shfl_xor(vr, 2, 64));
                    if (q == 0 && pc < 50) {
                        int oc = (r & 3) + 8 * (r >> 2) + 4 * hh;
                        pool1p[((size_t)(b * 16 + oc) * 54 + py + 2) * 56 + pc + 2] =
                            fmaxf(vr + bb[r], 0.f);
                    }
                }
            }
        }
    }

    gridbar(&cnt[2], t);

    // ============ Phase D: conv2 via MFMA (800 half-units, 2 per block-iter) ============
    for (int u = bid; u < 400; u += GRID_N) {
        __syncthreads();
        int half = t >> 7, lt = t & 127;
        int g = 2 * u + half;
        int b = (g & 7) * 4 + ((g >> 3) & 3);
        int py = g >> 5;
        {
            const float* src = pool1p + (size_t)b * 48384 + (2 * py) * 56;
            unsigned int* inb32 = (unsigned int*)sm.c2[half];
            for (int i = lt; i < 1344; i += 128) {
                int ic = i / 84, rem = i % 84;
                int r = rem / 14, c4 = rem % 14;
                float4 v = *(const float4*)(src + ic * 3024 + r * 56 + c4 * 4);
                inb32[i * 2 + 0] = pk2(v.x, v.y);
                inb32[i * 2 + 1] = pk2(v.z, v.w);
            }
        }
        __syncthreads();
        int lane = lt & 63;
        int h = lt >> 6;
        int hh = lane >> 5;
        int smn = lane & 31;
        int cbi = h * 32 + smn; if (cbi > 49) cbi = 49;
        int cbA = cbi, cbB = cbi + 56;
        int oc = smn;
        int wbase = hh * 128 + oc;

        f32x16 accA = {0.f,0.f,0.f,0.f,0.f,0.f,0.f,0.f,0.f,0.f,0.f,0.f,0.f,0.f,0.f,0.f};
        f32x16 accB = {0.f,0.f,0.f,0.f,0.f,0.f,0.f,0.f,0.f,0.f,0.f,0.f,0.f,0.f,0.f,0.f};
        #pragma unroll
        for (int s = 0; s < 25; ++s) {
            union { short8 v; unsigned int u[4]; } bw;
            bw.u[0] = wT2b[wbase + s * 256 + 0];
            bw.u[1] = wT2b[wbase + s * 256 + 32];
            bw.u[2] = wT2b[wbase + s * 256 + 64];
            bw.u[3] = wT2b[wbase + s * 256 + 96];
            unsigned short ua[8], ub[8];
            #pragma unroll
            for (int e = 0; e < 8; ++e) {
                int o = hh ? COFF(16 * s + 8 + e) : COFF(16 * s + e);
                ua[e] = sm.c2[half][cbA + o];
                ub[e] = sm.c2[half][cbB + o];
            }
            union { short8 v; unsigned int u[4]; } aA, aB;
            #pragma unroll
            for (int r = 0; r < 4; ++r) {
                aA.u[r] = (unsigned int)ua[2 * r] | ((unsigned int)ua[2 * r + 1] << 16);
                aB.u[r] = (unsigned int)ub[2 * r] | ((unsigned int)ub[2 * r + 1] << 16);
            }
            accA = __builtin_amdgcn_mfma_f32_32x32x16_bf16(aA.v, bw.v, accA, 0, 0, 0);
            accB = __builtin_amdgcn_mfma_f32_32x32x16_bf16(aB.v, bw.v, accB, 0, 0, 0);
        }
        float bias = c2b[oc];
        float* dst = pool2 + ((size_t)(b * 32 + oc) * 25 + py) * 25;
        #pragma unroll
        for (int q = 0; q < 4; ++q) {
            float m0 = fmaxf(fmaxf(accA[4 * q + 0], accB[4 * q + 0]),
                             fmaxf(accA[4 * q + 1], accB[4 * q + 1]));
            float m1 = fmaxf(fmaxf(accA[4 * q + 2], accB[4 * q + 2]),
                             fmaxf(accA[4 * q + 3], accB[4 * q + 3]));
            int px0 = h * 16 + 4 * q + 2 * hh;
            if (px0 < 25) dst[px0] = fmaxf(m0 + bias, 0.f);
            if (px0 + 1 < 25) dst[px0 + 1] = fmaxf(m1 + bias, 0.f);
        }
    }

    gridbar(&cnt[3], t);

    // ============ Phase E: final linear (320 units, <=2 per block) ============
    for (int u = bid; u < 320; u += GRID_N) {
        __syncthreads();
        int cls = u / BATCH, b = u % BATCH;
        const float4* y = (const float4*)(pool2 + (size_t)b * 20000);
        const float4* w = (const float4*)(oww + (size_t)cls * 20000);
        float acc = 0.f;
        for (int k = t; k < 5000; k += 256) {
            float4 a = y[k], ww = w[k];
            acc += a.x * ww.x + a.y * ww.y + a.z * ww.z + a.w * ww.w;
        }
        #pragma unroll
        for (int off = 32; off > 0; off >>= 1)
            acc += __shfl_xor(acc, off, 64);
        if ((t & 63) == 0) sm.fcpart[t >> 6] = acc;
        __syncthreads();
        if (t == 0)
            out[b * NCLS + cls] = sm.fcpart[0] + sm.fcpart[1] + sm.fcpart[2] +
                                  sm.fcpart[3] + owb[cls];
    }
}

extern "C" void kernel_launch(void* const* d_in, const int* in_sizes, int n_in,
                              void* d_out, int out_size, void* d_ws, size_t ws_size,
                              hipStream_t stream)
{
    const float* x   = (const float*)d_in[0];
    const int*   pi0 = (const int*)d_in[1];
    const int*   pi1 = (const int*)d_in[2];
    const float* w1  = (const float*)d_in[3];
    const float* b1  = (const float*)d_in[4];
    const float* w2  = (const float*)d_in[5];
    const float* b2  = (const float*)d_in[6];
    const float* c1w = (const float*)d_in[7];
    const float* c1b = (const float*)d_in[8];
    const float* c2w = (const float*)d_in[9];
    const float* c2b = (const float*)d_in[10];
    const float* oww = (const float*)d_in[11];
    const float* owb = (const float*)d_in[12];
    float* out = (float*)d_out;
    float* ws = (float*)d_ws;

    unsigned int* cnt  = (unsigned int*)(ws + CNT_OFF);
    unsigned int* maxb = (unsigned int*)(ws + MAXB_OFF);

    k_bz  <<<1, 256, 0, stream>>>(cnt, maxb);
    k_mega<<<GRID_N, 256, 0, stream>>>(x, pi0, pi1, w1, b1, w2, b2,
                                       c1w, c1b, c2w, c2b, oww, owb, out, ws);
}

// Round 19
// 63.467 us; speedup vs baseline: 4.4059x; 4.4059x over previous
//
#include <hip/hip_runtime.h>
#include <hip/hip_bf16.h>

#define N_NODES 16000
#define IN_F 128
#define HID 64
#define BATCH 32
#define NPAIR 128
#define DRES 100
#define NCLS 10

// workspace layout (float offsets)
#define NF_OFF     0
#define WA1_OFF    16000                 // conv1 A-frag bf16 pairs (512 uint)
#define WT2B_OFF   16800                 // [200 kp][32 oc] packed bf16 pairs (6400 uint)
#define MAXB_OFF   23264                 // [64] per-img max bits (zeroed in prep block)
#define IMGSP_OFF  23328                 // [32][2][104][104] padded
#define POOL1P_OFF 715552                // [32][16][54][56] padded
#define POOL2_OFF  2263840               // [32][32][25][25]

#define NFILT_BLK  125                   // filt blocks (4 waves x 32 nodes each)

typedef short short8 __attribute__((ext_vector_type(8)));
typedef float f32x16 __attribute__((ext_vector_type(16)));

static __device__ __forceinline__ unsigned short f2b(float f) {
    __hip_bfloat16 h = __float2bfloat16(f);
    return *reinterpret_cast<unsigned short*>(&h);
}
static __device__ __forceinline__ unsigned int pk2(float a, float b) {
    return (unsigned int)f2b(a) | ((unsigned int)f2b(b) << 16);
}

// conv2: element offset of k=(ic,kh,kw) within inb[16][6][56]
#define COFF(k) (((k)/25)*336 + (((k)%25)/5)*56 + ((k)%25)%5)
// conv1: element offset of k within inbz[2][6][104]; k>=50 -> zero zone @1248
#define C1OFF(k) ((k) < 50 ? ((k)/25)*624 + ((((k)%25)/5))*104 + (((k)%25)%5) : 1248)

// ---------------- Kernel IF: filt MLP (MFMA) + weight prep (NO border zeroing) ----------------
// Borders of imgs_p / pool1p are never zeroed; conv1/conv2 staging masks them
// in-register instead (reads of poisoned memory are discarded by select).
__global__ __launch_bounds__(256) void k_initfilt(
    const float* __restrict__ x, const float* __restrict__ w1,
    const float* __restrict__ b1, const float* __restrict__ w2,
    const float* __restrict__ b2, float* __restrict__ nf, float* __restrict__ out_nf,
    const float* __restrict__ c1w, const float* __restrict__ c2w,
    unsigned int* __restrict__ wA1, unsigned int* __restrict__ wT2b,
    unsigned int* __restrict__ maxb)
{
    int bx = blockIdx.x, t = threadIdx.x;
    if (bx < NFILT_BLK) {
        int wave = t >> 6, lane = t & 63;
        int n0 = ((bx << 2) + wave) * 32;
        int hh = lane >> 5, smn = lane & 31;
        const float* xr = x + (size_t)(n0 + smn) * IN_F + hh * 8;
        const float* wbase = w1 + hh * 512 + smn;

        f32x16 acc0 = {0.f,0.f,0.f,0.f,0.f,0.f,0.f,0.f,0.f,0.f,0.f,0.f,0.f,0.f,0.f,0.f};
        f32x16 acc1 = {0.f,0.f,0.f,0.f,0.f,0.f,0.f,0.f,0.f,0.f,0.f,0.f,0.f,0.f,0.f,0.f};
        #pragma unroll
        for (int s = 0; s < 8; ++s) {
            float4 v0 = *(const float4*)(xr + s * 16);
            float4 v1 = *(const float4*)(xr + s * 16 + 4);
            union { short8 v; unsigned int u[4]; } a;
            a.u[0] = pk2(v0.x, v0.y);
            a.u[1] = pk2(v0.z, v0.w);
            a.u[2] = pk2(v1.x, v1.y);
            a.u[3] = pk2(v1.z, v1.w);
            union { short8 v; unsigned int u[4]; } b0f, b1f;
            #pragma unroll
            for (int r = 0; r < 4; ++r) {
                float wa0 = wbase[s * 1024 + r * 128];
                float wb0 = wbase[s * 1024 + r * 128 + 64];
                float wa1 = wbase[s * 1024 + r * 128 + 32];
                float wb1v = wbase[s * 1024 + r * 128 + 96];
                b0f.u[r] = pk2(wa0, wb0);
                b1f.u[r] = pk2(wa1, wb1v);
            }
            acc0 = __builtin_amdgcn_mfma_f32_32x32x16_bf16(a.v, b0f.v, acc0, 0, 0, 0);
            acc1 = __builtin_amdgcn_mfma_f32_32x32x16_bf16(a.v, b1f.v, acc1, 0, 0, 0);
        }
        int h0 = smn, h1 = 32 + smn;
        float b10 = b1[h0], b11 = b1[h1], w20 = w2[h0], w21 = w2[h1];
        float q[16];
        #pragma unroll
        for (int r = 0; r < 16; ++r)
            q[r] = fmaxf(acc0[r] + b10, 0.f) * w20 + fmaxf(acc1[r] + b11, 0.f) * w21;
        #pragma unroll
        for (int off = 1; off < 32; off <<= 1) {
            #pragma unroll
            for (int r = 0; r < 16; ++r)
                q[r] += __shfl_xor(q[r], off, 64);
        }
        if (smn == 0) {
            float b2v = b2[0];
            #pragma unroll
            for (int r = 0; r < 16; ++r) {
                int m = (r & 3) + 8 * (r >> 2) + 4 * hh;
                float f = 1.f / (1.f + expf(-(q[r] + b2v)));
                nf[n0 + m] = f;
                out_nf[n0 + m] = f;
            }
        }
        return;
    }
    if (bx == NFILT_BLK) {
        if (t < 64) maxb[t] = 0u;
        for (int i = t; i < 512; i += 256) {
            int r = i & 3, m = (i >> 2) & 15, kg = (i >> 6) & 1, s = i >> 7;
            int k0 = s * 16 + kg * 8 + 2 * r;
            float f0 = (k0 < 50) ? c1w[m * 50 + k0] : 0.f;
            float f1 = (k0 + 1 < 50) ? c1w[m * 50 + k0 + 1] : 0.f;
            wA1[i] = pk2(f0, f1);
        }
        return;
    }
    // bx == NFILT_BLK + 1
    for (int i = t; i < 6400; i += 256) {
        int kp = i >> 5, oc = i & 31;
        int k0 = 2 * kp, k1 = k0 + 1;
        float f0 = c2w[(oc * 16 + k0 / 25) * 25 + k0 % 25];
        float f1 = c2w[(oc * 16 + k1 / 25) * 25 + k1 % 25];
        wT2b[i] = pk2(f0, f1);
    }
}

// ---------------- Kernel B: persistence image, 512 blocks (img, col-quarter, row-half) ----------------
__global__ __launch_bounds__(256) void k_pimg(const float* __restrict__ nf,
    const int* __restrict__ pi0, const int* __restrict__ pi1,
    float* __restrict__ imgs_p, unsigned int* __restrict__ maxb)
{
    int g = blockIdx.x;
    int img = (g & 7) * 8 + ((g >> 3) & 7);
    int q = (g >> 6) & 3;          // col quarter
    int rh = g >> 8;               // row half
    int b = img >> 1, c = img & 1;
    const int* pi = c ? pi1 : pi0;
    __shared__ float sb[NPAIR], sp[NPAIR];
    __shared__ float wm[4];
    int t = threadIdx.x;
    if (t < NPAIR) {
        int i0 = pi[(b * NPAIR + t) * 2 + 0];
        int i1 = pi[(b * NPAIR + t) * 2 + 1];
        float f0 = nf[i0], f1 = nf[i1];
        sb[t] = f0;
        sp[t] = f1 - f0;
    }
    __syncthreads();
    bool act = t < 169;
    int ti = t / 13, tj = t % 13;
    float acc[4][2] = {};
    if (act) {
        float ci[4];
        #pragma unroll
        for (int r = 0; r < 4; ++r) ci[r] = (float)(ti + 13 * (rh * 4 + r)) * 0.01f;
        float cj0 = (float)(q * 25 + tj) * 0.01f;
        float cj1 = (float)(q * 25 + tj + 13) * 0.01f;
        for (int p = 0; p < NPAIR; ++p) {
            float bb = sb[p], pp = sp[p];
            float d0 = pp - cj0, d1 = pp - cj1;
            float e0 = __expf(-d0 * d0), e1 = __expf(-d1 * d1);
            #pragma unroll
            for (int r = 0; r < 4; ++r) {
                float d = bb - ci[r];
                float eb = __expf(-d * d);
                acc[r][0] = fmaf(eb, e0, acc[r][0]);
                acc[r][1] = fmaf(eb, e1, acc[r][1]);
            }
        }
    }
    float lmax = 0.f;
    if (act) {
        float* dst = imgs_p + (size_t)img * 10816 + 2 * 104 + 2 + q * 25;
        #pragma unroll
        for (int r = 0; r < 4; ++r) {
            int i = ti + 13 * (rh * 4 + r);
            if (i < DRES) {
                dst[i * 104 + tj] = acc[r][0];
                lmax = fmaxf(lmax, acc[r][0]);
                if (tj < 12) {
                    dst[i * 104 + tj + 13] = acc[r][1];
                    lmax = fmaxf(lmax, acc[r][1]);
                }
            }
        }
    }
    #pragma unroll
    for (int off = 32; off > 0; off >>= 1)
        lmax = fmaxf(lmax, __shfl_xor(lmax, off, 64));
    if ((t & 63) == 0) wm[t >> 6] = lmax;
    __syncthreads();
    if (t == 0) {
        float bm = fmaxf(fmaxf(wm[0], wm[1]), fmaxf(wm[2], wm[3]));
        atomicMax(&maxb[img], __float_as_uint(bm));
    }
}

// ---------------- Kernel C: conv1 via MFMA implicit GEMM (border-masked staging) ----------------
__global__ __launch_bounds__(128) void k_conv1(const float* __restrict__ imgs_p,
    const unsigned int* __restrict__ wA1, const float* __restrict__ cb1,
    const unsigned int* __restrict__ maxb, float* __restrict__ pool1p)
{
    int g = blockIdx.x;
    int b = (g & 7) * 4 + ((g >> 3) & 3);
    int py = g >> 5;
    int t = threadIdx.x;

    __shared__ unsigned short inbz[1472];   // [2 ic][6 rows][104] bf16 + zero zone
    {
        float sc0 = 1.f / __uint_as_float(maxb[b * 2 + 0]);
        float sc1 = 1.f / __uint_as_float(maxb[b * 2 + 1]);
        const float* s0 = imgs_p + (size_t)(b * 2 + 0) * 10816 + (2 * py) * 104;
        const float* s1 = s0 + 10816;
        unsigned int* z32 = (unsigned int*)inbz;
        for (int i = t; i < 736; i += 128) {
            unsigned int val = 0u;
            if (i < 624) {
                int ic = (i < 312) ? 0 : 1;
                int s2 = (i < 312) ? 2 * i : 2 * i - 624;
                int r = s2 / 104, cc = s2 % 104;
                int pr = 2 * py + r;
                // interior of padded image: rows/cols in [2,102)
                if (pr >= 2 && pr < 102 && cc >= 2 && cc < 102) {
                    const float* sp_ = ic ? s1 : s0;
                    float sc = ic ? sc1 : sc0;
                    float2 v = *(const float2*)(sp_ + r * 104 + cc);
                    val = pk2(v.x * sc, v.y * sc);
                }
            }
            z32[i] = val;
        }
    }
    __syncthreads();

    int lane = t & 63;
    int h = t >> 6;
    int hh = lane >> 5;
    int sm = lane & 31;
    int q = lane & 3;
    int cl = sm >> 2;
    int laneoff = (q >> 1) * 104 + 2 * cl + (q & 1);

    uint4 z4 = {0u, 0u, 0u, 0u};
    union { short8 v; uint4 qd; } afr[4];
    #pragma unroll
    for (int s = 0; s < 4; ++s)
        afr[s].qd = (sm < 16) ? *(const uint4*)(wA1 + ((s * 2 + hh) * 16 + sm) * 4) : z4;

    float bb[8];
    #pragma unroll
    for (int r = 0; r < 8; ++r)
        bb[r] = cb1[(r & 3) + 8 * (r >> 2) + 4 * hh];

    #pragma unroll
    for (int tt = 0; tt < 4; ++tt) {
        int t_ = h + 2 * tt;
        if (t_ < 7) {
            const unsigned short* bp = inbz + laneoff + 16 * t_;
            f32x16 acc = {0.f,0.f,0.f,0.f,0.f,0.f,0.f,0.f,0.f,0.f,0.f,0.f,0.f,0.f,0.f,0.f};
            #pragma unroll
            for (int s = 0; s < 4; ++s) {
                unsigned short ub[8];
                #pragma unroll
                for (int e = 0; e < 8; ++e) {
                    int off = hh ? C1OFF(16 * s + 8 + e) : C1OFF(16 * s + e);
                    ub[e] = bp[off];
                }
                union { short8 v; unsigned int u[4]; } bf;
                #pragma unroll
                for (int r = 0; r < 4; ++r)
                    bf.u[r] = (unsigned int)ub[2 * r] | ((unsigned int)ub[2 * r + 1] << 16);
                acc = __builtin_amdgcn_mfma_f32_32x32x16_bf16(afr[s].v, bf.v, acc, 0, 0, 0);
            }
            int pc = 8 * t_ + cl;
            #pragma unroll
            for (int r = 0; r < 8; ++r) {
                float vr = acc[r];
                vr = fmaxf(vr, __shfl_xor(vr, 1, 64));
                vr = fmaxf(vr, __shfl_xor(vr, 2, 64));
                if (q == 0 && pc < 50) {
                    int oc = (r & 3) + 8 * (r >> 2) + 4 * hh;
                    pool1p[((size_t)(b * 16 + oc) * 54 + py + 2) * 56 + pc + 2] =
                        fmaxf(vr + bb[r], 0.f);
                }
            }
        }
    }
}

// ---------------- Kernel D: conv2 via MFMA implicit GEMM (border-masked staging) ----------------
__global__ __launch_bounds__(128) void k_conv2(const float* __restrict__ pool1p,
    const unsigned int* __restrict__ wg, const float* __restrict__ cb2,
    float* __restrict__ pool2)
{
    int g = blockIdx.x;
    int b = (g & 7) * 4 + ((g >> 3) & 3);
    int py = g >> 5;
    int t = threadIdx.x;

    __shared__ unsigned short inb[5376];  // [16 ic][6 rows][56 cols] bf16
    {
        const float* src = pool1p + (size_t)b * 48384 + (2 * py) * 56;
        unsigned int* inb32 = (unsigned int*)inb;
        for (int i = t; i < 1344; i += 128) {
            int ic = i / 84, rem = i % 84;
            int r = rem / 14, c4 = rem % 14;
            int pr = 2 * py + r;
            float4 v = *(const float4*)(src + ic * 3024 + r * 56 + c4 * 4);
            // pool1p interior: rows/cols in [2,52)
            bool rv = (pr >= 2 && pr < 52);
            int c0 = c4 * 4;
            float x0 = (rv && c0 + 0 >= 2 && c0 + 0 < 52) ? v.x : 0.f;
            float y0 = (rv && c0 + 1 >= 2 && c0 + 1 < 52) ? v.y : 0.f;
            float z0 = (rv && c0 + 2 >= 2 && c0 + 2 < 52) ? v.z : 0.f;
            float w0 = (rv && c0 + 3 >= 2 && c0 + 3 < 52) ? v.w : 0.f;
            inb32[i * 2 + 0] = pk2(x0, y0);
            inb32[i * 2 + 1] = pk2(z0, w0);
        }
    }
    __syncthreads();

    int lane = t & 63;
    int h = t >> 6;
    int hh = lane >> 5;
    int sm = lane & 31;
    int cbi = h * 32 + sm; if (cbi > 49) cbi = 49;
    int cbA = cbi, cbB = cbi + 56;
    int oc = sm;
    int wbase = hh * 128 + oc;

    f32x16 accA = {0.f,0.f,0.f,0.f,0.f,0.f,0.f,0.f,0.f,0.f,0.f,0.f,0.f,0.f,0.f,0.f};
    f32x16 accB = {0.f,0.f,0.f,0.f,0.f,0.f,0.f,0.f,0.f,0.f,0.f,0.f,0.f,0.f,0.f,0.f};

    #pragma unroll
    for (int s = 0; s < 25; ++s) {
        union { short8 v; unsigned int u[4]; } bw;
        bw.u[0] = wg[wbase + s * 256 + 0];
        bw.u[1] = wg[wbase + s * 256 + 32];
        bw.u[2] = wg[wbase + s * 256 + 64];
        bw.u[3] = wg[wbase + s * 256 + 96];
        unsigned short ua[8], ub[8];
        #pragma unroll
        for (int e = 0; e < 8; ++e) {
            int o = hh ? COFF(16 * s + 8 + e) : COFF(16 * s + e);
            ua[e] = inb[cbA + o];
            ub[e] = inb[cbB + o];
        }
        union { short8 v; unsigned int u[4]; } aA, aB;
        #pragma unroll
        for (int r = 0; r < 4; ++r) {
            aA.u[r] = (unsigned int)ua[2 * r] | ((unsigned int)ua[2 * r + 1] << 16);
            aB.u[r] = (unsigned int)ub[2 * r] | ((unsigned int)ub[2 * r + 1] << 16);
        }
        accA = __builtin_amdgcn_mfma_f32_32x32x16_bf16(aA.v, bw.v, accA, 0, 0, 0);
        accB = __builtin_amdgcn_mfma_f32_32x32x16_bf16(aB.v, bw.v, accB, 0, 0, 0);
    }

    float bias = cb2[oc];
    float* dst = pool2 + ((size_t)(b * 32 + oc) * 25 + py) * 25;
    #pragma unroll
    for (int q = 0; q < 4; ++q) {
        float m0 = fmaxf(fmaxf(accA[4 * q + 0], accB[4 * q + 0]),
                         fmaxf(accA[4 * q + 1], accB[4 * q + 1]));
        float m1 = fmaxf(fmaxf(accA[4 * q + 2], accB[4 * q + 2]),
                         fmaxf(accA[4 * q + 3], accB[4 * q + 3]));
        int px0 = h * 16 + 4 * q + 2 * hh;
        if (px0 < 25) dst[px0] = fmaxf(m0 + bias, 0.f);
        if (px0 + 1 < 25) dst[px0 + 1] = fmaxf(m1 + bias, 0.f);
    }
}

// ---------------- Kernel E: final linear (float4) ----------------
__global__ __launch_bounds__(256) void k_fc(const float* __restrict__ pool2,
    const float* __restrict__ oww, const float* __restrict__ ob,
    float* __restrict__ yhat)
{
    int cls = blockIdx.x / BATCH, b = blockIdx.x % BATCH;
    int t = threadIdx.x;
    const float4* y = (const float4*)(pool2 + (size_t)b * 20000);
    const float4* w = (const float4*)(oww + (size_t)cls * 20000);
    float acc = 0.f;
    for (int k = t; k < 5000; k += 256) {
        float4 a = y[k], ww = w[k];
        acc += a.x * ww.x + a.y * ww.y + a.z * ww.z + a.w * ww.w;
    }
    #pragma unroll
    for (int off = 32; off > 0; off >>= 1)
        acc += __shfl_xor(acc, off, 64);
    __shared__ float part[4];
    if ((t & 63) == 0) part[t >> 6] = acc;
    __syncthreads();
    if (t == 0)
        yhat[b * NCLS + cls] = part[0] + part[1] + part[2] + part[3] + ob[cls];
}

extern "C" void kernel_launch(void* const* d_in, const int* in_sizes, int n_in,
                              void* d_out, int out_size, void* d_ws, size_t ws_size,
                              hipStream_t stream)
{
    const float* x   = (const float*)d_in[0];
    const int*   pi0 = (const int*)d_in[1];
    const int*   pi1 = (const int*)d_in[2];
    const float* w1  = (const float*)d_in[3];
    const float* b1  = (const float*)d_in[4];
    const float* w2  = (const float*)d_in[5];
    const float* b2  = (const float*)d_in[6];
    const float* c1w = (const float*)d_in[7];
    const float* c1b = (const float*)d_in[8];
    const float* c2w = (const float*)d_in[9];
    const float* c2b = (const float*)d_in[10];
    const float* oww = (const float*)d_in[11];
    const float* owb = (const float*)d_in[12];
    float* out = (float*)d_out;
    float* ws = (float*)d_ws;

    float*        nf     = ws + NF_OFF;
    unsigned int* wA1    = (unsigned int*)(ws + WA1_OFF);
    unsigned int* wT2b   = (unsigned int*)(ws + WT2B_OFF);
    unsigned int* maxb   = (unsigned int*)(ws + MAXB_OFF);
    float*        imgs_p = ws + IMGSP_OFF;
    float*        pool1p = ws + POOL1P_OFF;
    float*        pool2  = ws + POOL2_OFF;

    k_initfilt<<<NFILT_BLK + 2, 256, 0, stream>>>(
        x, w1, b1, w2, b2, nf, out + BATCH * NCLS,
        c1w, c2w, wA1, wT2b, maxb);
    k_pimg <<<512, 256, 0, stream>>>(nf, pi0, pi1, imgs_p, maxb);
    k_conv1<<<1600, 128, 0, stream>>>(imgs_p, wA1, c1b, maxb, pool1p);
    k_conv2<<<800, 128, 0, stream>>>(pool1p, wT2b, c2b, pool2);
    k_fc   <<<BATCH * NCLS, 256, 0, stream>>>(pool2, oww, owb, out);
}